// Round 19
// baseline (28054.846 us; speedup 1.0000x reference)
//
#include <hip/hip_runtime.h>

#define HH 1024
#define TT 4096
#define NWG 256
#define NWG_PER_LAYER 128
#define JS_PER_WG 8     // 1024 / 128
#define JS_PER_WAVE 2   // 8 j's / 4 waves
#define LDS_BYTES 131072  // 4 waves * 8 rows * 1024 floats * 4 B (w_hh tile)

__device__ __forceinline__ float fsigmoid(float x) {
    return 1.0f / (1.0f + __expf(-x));
}
__device__ __forceinline__ float ftanh(float x) {
    float ax = fabsf(x);
    float e = __expf(-2.0f * ax);
    float t = (1.0f - e) / (1.0f + e);
    return copysignf(t, x);
}
__device__ __forceinline__ void fma4(float& a, const float4 w, const float4 v) {
    a = fmaf(w.x, v.x, a);
    a = fmaf(w.y, v.y, a);
    a = fmaf(w.z, v.z, a);
    a = fmaf(w.w, v.w, a);
}

// ---- (value, epoch) pair primitives ------------------------------------
// Pair = 8B {f32 value, u32 tag}; the 8B single-copy-atomic store publishes
// value WITH tag (tag-visible => value-visible). Role here (r19): pairs are
// NOT the detection mechanism (r15/r16 lesson: fat polls collapse the LLC) --
// detection stays with the thin slot barrier. Pairs exist so the producer
// need not DRAIN its stores before arriving: consumers verify tags on the
// one-shot load after detect and retry in the (rare) not-yet-landed window.

__device__ __forceinline__ void publish_pair(void* base, int jbase,
                                             float h0, float h1, unsigned tag) {
    const unsigned long long w0 =
        ((unsigned long long)tag << 32) | (unsigned long long)__float_as_uint(h0);
    const unsigned long long w1 =
        ((unsigned long long)tag << 32) | (unsigned long long)__float_as_uint(h1);
    unsigned long long* p =
        (unsigned long long*)((char*)base + (size_t)jbase * 8);
    __hip_atomic_store(p,     w0, __ATOMIC_RELAXED, __HIP_MEMORY_SCOPE_AGENT);
    __hip_atomic_store(p + 1, w1, __ATOMIC_RELAXED, __HIP_MEMORY_SCOPE_AGENT);
}

#define PAIR_UNPACK(v, a0,a1,a2,a3,a4,a5,a6,a7) \
    v[0] = make_float4(__uint_as_float(a0.x), __uint_as_float(a0.z), \
                       __uint_as_float(a1.x), __uint_as_float(a1.z)); \
    v[1] = make_float4(__uint_as_float(a2.x), __uint_as_float(a2.z), \
                       __uint_as_float(a3.x), __uint_as_float(a3.z)); \
    v[2] = make_float4(__uint_as_float(a4.x), __uint_as_float(a4.z), \
                       __uint_as_float(a5.x), __uint_as_float(a5.z)); \
    v[3] = make_float4(__uint_as_float(a6.x), __uint_as_float(a6.z), \
                       __uint_as_float(a7.x), __uint_as_float(a7.z));

#define TAGS_OK(e, a0,a1,a2,a3,a4,a5,a6,a7) \
    ((a0.y==e)&(a0.w==e)&(a1.y==e)&(a1.w==e)&(a2.y==e)&(a2.w==e)& \
     (a3.y==e)&(a3.w==e)&(a4.y==e)&(a4.w==e)&(a5.y==e)&(a5.w==e)& \
     (a6.y==e)&(a6.w==e)&(a7.y==e)&(a7.w==e))

// Verified one-shot pair load (16 pairs = 128B/lane, 8 pipelined dwordx4,
// one vmcnt). Expected to succeed on attempt 1 -- the loop is the safety net
// for the no-drain publish window.
__device__ __forceinline__ void pair_read(float4 v[4], const void* base,
                                          unsigned expect) {
    const char* p = (const char*)base + (size_t)(threadIdx.x & 63) * 128;
    for (;;) {
        uint4 a0, a1, a2, a3, a4, a5, a6, a7;
        asm volatile(
            "global_load_dwordx4 %0, %8, off sc0 sc1\n\t"
            "global_load_dwordx4 %1, %8, off offset:16 sc0 sc1\n\t"
            "global_load_dwordx4 %2, %8, off offset:32 sc0 sc1\n\t"
            "global_load_dwordx4 %3, %8, off offset:48 sc0 sc1\n\t"
            "global_load_dwordx4 %4, %8, off offset:64 sc0 sc1\n\t"
            "global_load_dwordx4 %5, %8, off offset:80 sc0 sc1\n\t"
            "global_load_dwordx4 %6, %8, off offset:96 sc0 sc1\n\t"
            "global_load_dwordx4 %7, %8, off offset:112 sc0 sc1\n\t"
            "s_waitcnt vmcnt(0)"
            : "=&v"(a0), "=&v"(a1), "=&v"(a2), "=&v"(a3),
              "=&v"(a4), "=&v"(a5), "=&v"(a6), "=&v"(a7)
            : "v"(p) : "memory");
        const bool ok = TAGS_OK(expect, a0,a1,a2,a3,a4,a5,a6,a7);
        if (__all((int)ok)) { PAIR_UNPACK(v, a0,a1,a2,a3,a4,a5,a6,a7); return; }
        __builtin_amdgcn_s_sleep(1);
    }
}

// r13-proven thin slot barrier: lane l reads slots[4l..4l+3] with one dwordx4
// sc0 sc1 (64 lanes = all 256 slots = one LLC RT per attempt).
__device__ __forceinline__ void slot_barrier_wait(const unsigned* slots, unsigned tgt) {
    const unsigned* p = slots + 4 * (threadIdx.x & 63);
    for (;;) {
        uint4 v;
        asm volatile(
            "global_load_dwordx4 %0, %1, off sc0 sc1\n\t"
            "s_waitcnt vmcnt(0)"
            : "=&v"(v) : "v"(p) : "memory");
        const unsigned m = min(min(v.x, v.y), min(v.z, v.w));
        if (__all(m >= tgt)) break;
        __builtin_amdgcn_s_sleep(1);
    }
}

#define FOR_R(F) F(0) F(1) F(2) F(3) F(4) F(5) F(6) F(7)

// Persistent 2-layer LSTM = round-13 skeleton + drain-free arrive (r19).
// WGs [0,128): layer 0 (t = k). WGs [128,256): layer 1 (t = k-2, skew 2).
// Per step: CRITICAL {verified pair read h[t-1] -> w_hh GEMV (LDS) -> reduce
// -> +bias -> gates -> publish (h,tag) pairs} -> raw s_barrier (converges the
// 4 waves, NO vmcnt drain -- the r19 change; publish-issue order is pinned by
// "memory" clobbers) -> ARRIVE (tid0: slot[wg]=k+1, issued ~1 store-RT
// earlier than r13) -> SLACK {gx[t+1]; L1 verified-pair-reads h1[tn]} ->
// POLL (thin slot barrier, full coupling).
//   w_hh: 128 KB LDS [wave][row][q][lane] (conflict-free ds_read_b128)
//   w_ih: streamed from global (L2-resident) every step, in slack
//   h1: pair ring R1[4][8192B] (L0 publishes; L0 recurrence + L1 input)
//   h2: pair ring R2[4][8192B] (L1 publishes; L1 recurrence); out write-only
__global__ __launch_bounds__(256, 1) void lstm2_persistent(
    const float* __restrict__ x,
    const float* __restrict__ wih0, const float* __restrict__ whh0,
    const float* __restrict__ bih0, const float* __restrict__ bhh0,
    const float* __restrict__ wih1, const float* __restrict__ whh1,
    const float* __restrict__ bih1, const float* __restrict__ bhh1,
    float* __restrict__ out,     // [T][H] h2 (plain output, write-only)
    char* __restrict__ r1,       // R1 pair ring, 4 * 8192 B
    char* __restrict__ r2,       // R2 pair ring, 4 * 8192 B
    unsigned* __restrict__ slots)     // 256 per-WG epoch slots (zeroed)
{
    extern __shared__ float ldsw[];   // w_hh tile, 128 KB

    const int wg   = blockIdx.x;
    const int tid  = threadIdx.x;
    const int wave = tid >> 6;
    const int lane = tid & 63;
    const bool isL1 = (wg >= NWG_PER_LAYER);
    const int wgl   = isL1 ? (wg - NWG_PER_LAYER) : wg;
    const int jbase = wgl * JS_PER_WG + wave * JS_PER_WAVE;
    const int col   = lane * 16;   // this lane's 16-elem chunk of the 1024-vector

    const float* wih = isL1 ? wih1 : wih0;
    const float* whh = isL1 ? whh1 : whh0;
    const float* bih = isL1 ? bih1 : bih0;
    const float* bhh = isL1 ? bhh1 : bhh0;
    char* rrec = isL1 ? r2 : r1;   // ring this layer's recurrence reads/writes

    // ---- stage w_hh into LDS: float offset = wave*8192 + r*1024 + q*256 + lane*4
    #pragma unroll
    for (int r = 0; r < 8; ++r) {
        const int row = (r & 3) * HH + (jbase + (r >> 2));
        const float4* p  = (const float4*)(whh + (size_t)row * HH + col);
        float*       wb = ldsw + wave * 8192 + r * 1024 + lane * 4;
        #pragma unroll
        for (int q = 0; q < 4; ++q)
            *(float4*)(wb + q * 256) = p[q];
    }

    // ---- bias (applied AFTER the butterfly reduce, uniform across lanes) ----
    #define DECLB(r) float B##r; { const int row = ((r)&3)*HH + (jbase + ((r)>>2)); \
                                   B##r = bih[row] + bhh[row]; }
    FOR_R(DECLB)

    // gx per-lane partials, carried in registers across the step boundary
    #define DECLG(r) float gxp##r = 0.0f;
    FOR_R(DECLG)

    float c0v = 0.0f, c1v = 0.0f;
    int loff  = wave * 8192 + lane * 4;  // LDS float offset (pinned per iter)
    int wioff = 0;                       // global w_ih offset (pinned per iter)

    // streamed input-GEMV partial: gxp_r = w_ih[rows(r)][col..col+16) @ iv
    // (NO bias here -- per-lane partials get summed 64x by the reduce)
    #define GXR(r) { \
        const int row = ((r) & 3) * HH + (jbase + ((r) >> 2)); \
        const float4* wp = (const float4*)(wih + (size_t)row * HH + col + wioff); \
        float4 w0 = wp[0], w1 = wp[1], w2 = wp[2], w3 = wp[3]; \
        float a = 0.0f; \
        fma4(a, w0, iv4[0]); fma4(a, w1, iv4[1]); \
        fma4(a, w2, iv4[2]); fma4(a, w3, iv4[3]); \
        gxp##r = a; }

    // ---- prologue: L0 needs gx[0] before the first step ----
    if (!isL1) {
        float4 iv4[4];
        const float4* p = (const float4*)(x + col);
        iv4[0] = p[0]; iv4[1] = p[1]; iv4[2] = p[2]; iv4[3] = p[3];
        FOR_R(GXR)
    }

    __syncthreads();   // LDS w_hh tile ready (full barrier: staging must drain)

    for (int k = 0; k <= TT + 1; ++k) {
        // per-iteration pins: block LICM of the (address-invariant) LDS w_hh
        // reads and global w_ih loads into spillable long-lived registers
        asm volatile("" : "+v"(loff), "+v"(wioff));

        const int t = isL1 ? (k - 2) : k;

        // ================= CRITICAL phase =================
        if (t >= 0 && t < TT) {
            float4 hp4[4];
            if (t > 0) {
                // verified pair read: h[t-1], tag t (1 RT; retry = safety net)
                pair_read(hp4, rrec + (size_t)((t - 1) & 3) * 8192, (unsigned)t);
            } else {
                hp4[0] = hp4[1] = hp4[2] = hp4[3] = make_float4(0.f, 0.f, 0.f, 0.f);
            }

            float acc0, acc1, acc2, acc3, acc4, acc5, acc6, acc7;
            #define DOTW(r) { float a = gxp##r; \
                const float4* wp = (const float4*)(ldsw + loff + (r) * 1024); \
                fma4(a, wp[0],   hp4[0]); fma4(a, wp[64],  hp4[1]); \
                fma4(a, wp[128], hp4[2]); fma4(a, wp[192], hp4[3]); \
                acc##r = a; }
            FOR_R(DOTW)

            #define REDW(m) \
                acc0 += __shfl_xor(acc0, m, 64); acc1 += __shfl_xor(acc1, m, 64); \
                acc2 += __shfl_xor(acc2, m, 64); acc3 += __shfl_xor(acc3, m, 64); \
                acc4 += __shfl_xor(acc4, m, 64); acc5 += __shfl_xor(acc5, m, 64); \
                acc6 += __shfl_xor(acc6, m, 64); acc7 += __shfl_xor(acc7, m, 64);
            REDW(1) REDW(2) REDW(4) REDW(8) REDW(16) REDW(32)

            // gates (PyTorch order i,f,g,o); bias added post-reduce
            const float gi0 = fsigmoid(acc0 + B0), gf0 = fsigmoid(acc1 + B1);
            const float gg0 = ftanh(acc2 + B2),    go0 = fsigmoid(acc3 + B3);
            c0v = gf0 * c0v + gi0 * gg0;
            const float h0 = go0 * ftanh(c0v);
            const float gi1 = fsigmoid(acc4 + B4), gf1 = fsigmoid(acc5 + B5);
            const float gg1 = ftanh(acc6 + B6),    go1 = fsigmoid(acc7 + B7);
            c1v = gf1 * c1v + gi1 * gg1;
            const float h1v = go1 * ftanh(c1v);

            if (lane == 0) {
                publish_pair(rrec + (size_t)(t & 3) * 8192, jbase, h0, h1v,
                             (unsigned)(t + 1));
                if (isL1)   // plain output store (recurrence reads R2, not out)
                    *(float2*)(out + (size_t)t * HH + jbase) = make_float2(h0, h1v);
            }
        }

        // Converge the WG's 4 waves WITHOUT draining stores (r19 change:
        // tags make the drain unnecessary; "memory" clobber pins issue order
        // of the publishes before the barrier and the arrive after it).
        asm volatile("s_barrier" ::: "memory");

        if (k <= TT) {
            // ===== ARRIVE: plain per-WG epoch store, no prior vmcnt wait =====
            if (tid == 0)
                __hip_atomic_store(&slots[wg], (unsigned)(k + 1),
                                   __ATOMIC_RELAXED, __HIP_MEMORY_SCOPE_AGENT);

            // ================= SLACK phase: gx for next timestep =============
            {
                const int tn = t + 1;
                if (tn >= 0 && tn < TT) {
                    float4 iv4[4];
                    if (!isL1) {
                        const float4* p = (const float4*)(x + (size_t)tn * HH + col);
                        iv4[0] = p[0]; iv4[1] = p[1]; iv4[2] = p[2]; iv4[3] = p[3];
                    } else {
                        // h1[tn] pairs (tag tn+1), published by L0 at step tn
                        // >= 1 full step ago -- verified read, 1st-attempt
                        pair_read(iv4, r1 + (size_t)(tn & 3) * 8192,
                                  (unsigned)(tn + 1));
                    }
                    FOR_R(GXR)
                }
            }
            // anchor gx results so the slack work cannot sink past the poll
            asm volatile("" : "+v"(gxp0), "+v"(gxp1), "+v"(gxp2), "+v"(gxp3),
                             "+v"(gxp4), "+v"(gxp5), "+v"(gxp6), "+v"(gxp7));

            // ================= POLL: all 256 slots >= k+1 (thin) =============
            slot_barrier_wait(slots, (unsigned)(k + 1));
        }
    }
}

extern "C" void kernel_launch(void* const* d_in, const int* in_sizes, int n_in,
                              void* d_out, int out_size, void* d_ws, size_t ws_size,
                              hipStream_t stream) {
    (void)in_sizes; (void)n_in; (void)out_size; (void)ws_size;
    const float* x    = (const float*)d_in[0];
    const float* wih0 = (const float*)d_in[1];
    const float* whh0 = (const float*)d_in[2];
    const float* bih0 = (const float*)d_in[3];
    const float* bhh0 = (const float*)d_in[4];
    const float* wih1 = (const float*)d_in[5];
    const float* whh1 = (const float*)d_in[6];
    const float* bih1 = (const float*)d_in[7];
    const float* bhh1 = (const float*)d_in[8];
    float* out = (float*)d_out;

    // ws layout: [0,1024) slots (256 x 4B) | [4096,36864) R1 pair ring |
    //            [36864,69632) R2 pair ring
    unsigned* slots = (unsigned*)d_ws;
    char*     r1    = (char*)d_ws + 4096;
    char*     r2    = (char*)d_ws + 36864;

    // allow 128 KB dynamic LDS (160 KB available per CU on gfx950)
    (void)hipFuncSetAttribute((const void*)lstm2_persistent,
                              hipFuncAttributeMaxDynamicSharedMemorySize, LDS_BYTES);

    // zero slots + both pair rings every call (clears stale tags between
    // replays -- harness does not re-poison d_ws)
    (void)hipMemsetAsync(d_ws, 0, 69632, stream);

    hipLaunchKernelGGL(lstm2_persistent, dim3(NWG), dim3(256), LDS_BYTES, stream,
                       x, wih0, whh0, bih0, bhh0,
                       wih1, whh1, bih1, bhh1, out, r1, r2, slots);
}

// Round 20
// 15529.204 us; speedup vs baseline: 1.8066x; 1.8066x over previous
//
#include <hip/hip_runtime.h>

#define HH 1024
#define TT 4096
#define NWG 256
#define NWG_PER_LAYER 128
#define JS_PER_WG 8     // 1024 / 128
#define JS_PER_WAVE 2   // 8 j's / 4 waves
#define LDS_BYTES 131072  // 4 waves * 8 rows * 1024 floats * 4 B (w_hh tile)

__device__ __forceinline__ float fsigmoid(float x) {
    return 1.0f / (1.0f + __expf(-x));
}
__device__ __forceinline__ float ftanh(float x) {
    float ax = fabsf(x);
    float e = __expf(-2.0f * ax);
    float t = (1.0f - e) / (1.0f + e);
    return copysignf(t, x);
}
__device__ __forceinline__ void fma4(float& a, const float4 w, const float4 v) {
    a = fmaf(w.x, v.x, a);
    a = fmaf(w.y, v.y, a);
    a = fmaf(w.z, v.z, a);
    a = fmaf(w.w, v.w, a);
}

// LLC-coherent 64B load, ONE round-trip (round-11 proven).
__device__ __forceinline__ void load64B_llc(float4 v[4], const float* p) {
    asm volatile(
        "global_load_dwordx4 %0, %4, off sc0 sc1\n\t"
        "global_load_dwordx4 %1, %4, off offset:16 sc0 sc1\n\t"
        "global_load_dwordx4 %2, %4, off offset:32 sc0 sc1\n\t"
        "global_load_dwordx4 %3, %4, off offset:48 sc0 sc1\n\t"
        "s_waitcnt vmcnt(0)"
        : "=&v"(v[0]), "=&v"(v[1]), "=&v"(v[2]), "=&v"(v[3])
        : "v"(p)
        : "memory");
}

// r13-proven thin slot barrier: lane l reads slots[4l..4l+3] with one dwordx4
// sc0 sc1 (64 lanes = all 256 slots = one LLC RT per attempt). r15/r16/r19
// law: any poll loop must stay <=16B/lane; data loads are issued once.
__device__ __forceinline__ void slot_barrier_wait(const unsigned* slots, unsigned tgt) {
    const unsigned* p = slots + 4 * (threadIdx.x & 63);
    for (;;) {
        uint4 v;
        asm volatile(
            "global_load_dwordx4 %0, %1, off sc0 sc1\n\t"
            "s_waitcnt vmcnt(0)"
            : "=&v"(v) : "v"(p) : "memory");
        const unsigned m = min(min(v.x, v.y), min(v.z, v.w));
        if (__all(m >= tgt)) break;
        __builtin_amdgcn_s_sleep(1);
    }
}

#define FOR_R(F) F(0) F(1) F(2) F(3) F(4) F(5) F(6) F(7)

// Persistent 2-layer LSTM = round-13 skeleton + AGPR-resident w_ih (r20).
// WGs [0,128): layer 0 (t = k). WGs [128,256): layer 1 (t = k-2, skew 2).
// Per step: CRITICAL {1-RT h load -> w_hh GEMV (LDS) -> reduce -> +bias ->
// gates -> store h} [byte-identical to r13] -> syncthreads -> ARRIVE (tid0:
// slot[wg]=k+1) -> SLACK {gx[t+1] = w_ih @ iv, w_ih read from AGPRs: 128
// v_accvgpr_read + 128 FMA ~ 0.2us, replacing r13's ~1us L2 stream of
// 128 KB/WG/step} -> POLL (thin, full coupling).
// r7 lesson applied correctly: AGPR reads belong in the slack phase (replace
// L2 latency), NOT the critical path (r7 put them on w_hh -> regressed).
//   w_hh: 128 KB LDS [wave][row][q][lane] (conflict-free ds_read_b128)
//   w_ih: 128 AGPRs/lane (one-time v_accvgpr_write; unified RF 512/wave)
//   h1: plain ring [4][1024]; h2 recurrence reads `out` directly.
__global__ __launch_bounds__(256, 1) void lstm2_persistent(
    const float* __restrict__ x,
    const float* __restrict__ wih0, const float* __restrict__ whh0,
    const float* __restrict__ bih0, const float* __restrict__ bhh0,
    const float* __restrict__ wih1, const float* __restrict__ whh1,
    const float* __restrict__ bih1, const float* __restrict__ bhh1,
    float* __restrict__ out,     // [T][H]  h2 (output + h2 recurrence buffer)
    float* __restrict__ ring,    // [4][H]  h1 ring (layer0 <-> layer1)
    const float* __restrict__ zbuf,   // [H] zeros (h[-1])
    unsigned* __restrict__ slots)     // 256 per-WG epoch slots (zeroed)
{
    extern __shared__ float ldsw[];   // w_hh tile, 128 KB

    const int wg   = blockIdx.x;
    const int tid  = threadIdx.x;
    const int wave = tid >> 6;
    const int lane = tid & 63;
    const bool isL1 = (wg >= NWG_PER_LAYER);
    const int wgl   = isL1 ? (wg - NWG_PER_LAYER) : wg;
    const int jbase = wgl * JS_PER_WG + wave * JS_PER_WAVE;
    const int col   = lane * 16;   // this lane's 16-elem chunk of the 1024-vector

    const float* wih = isL1 ? wih1 : wih0;
    const float* whh = isL1 ? whh1 : whh0;
    const float* bih = isL1 ? bih1 : bih0;
    const float* bhh = isL1 ? bhh1 : bhh0;

    // ---- stage w_hh into LDS: float offset = wave*8192 + r*1024 + q*256 + lane*4
    #pragma unroll
    for (int r = 0; r < 8; ++r) {
        const int row = (r & 3) * HH + (jbase + (r >> 2));
        const float4* p  = (const float4*)(whh + (size_t)row * HH + col);
        float*       wb = ldsw + wave * 8192 + r * 1024 + lane * 4;
        #pragma unroll
        for (int q = 0; q < 4; ++q)
            *(float4*)(wb + q * 256) = p[q];
    }

    // ---- w_ih into AGPRs: 8 rows x 16 floats = 128 AGPRs per lane ----
    #define DECLA(r) float AI##r##_0, AI##r##_1, AI##r##_2,  AI##r##_3, \
                           AI##r##_4, AI##r##_5, AI##r##_6,  AI##r##_7, \
                           AI##r##_8, AI##r##_9, AI##r##_10, AI##r##_11, \
                           AI##r##_12, AI##r##_13, AI##r##_14, AI##r##_15;
    FOR_R(DECLA)

    #define AW(dst, s) asm volatile("v_accvgpr_write_b32 %0, %1" : "=a"(dst) : "v"(s));
    #define AWI(r) { \
        const int row = ((r) & 3) * HH + (jbase + ((r) >> 2)); \
        const float4* pw = (const float4*)(wih + (size_t)row * HH + col); \
        float4 w0 = pw[0], w1 = pw[1], w2 = pw[2], w3 = pw[3]; \
        AW(AI##r##_0,  w0.x) AW(AI##r##_1,  w0.y) AW(AI##r##_2,  w0.z) AW(AI##r##_3,  w0.w) \
        AW(AI##r##_4,  w1.x) AW(AI##r##_5,  w1.y) AW(AI##r##_6,  w1.z) AW(AI##r##_7,  w1.w) \
        AW(AI##r##_8,  w2.x) AW(AI##r##_9,  w2.y) AW(AI##r##_10, w2.z) AW(AI##r##_11, w2.w) \
        AW(AI##r##_12, w3.x) AW(AI##r##_13, w3.y) AW(AI##r##_14, w3.z) AW(AI##r##_15, w3.w) }
    FOR_R(AWI)

    // ---- bias (applied AFTER the butterfly reduce, uniform across lanes) ----
    #define DECLB(r) float B##r; { const int row = ((r)&3)*HH + (jbase + ((r)>>2)); \
                                   B##r = bih[row] + bhh[row]; }
    FOR_R(DECLB)

    // gx per-lane partials, carried in registers across the step boundary
    #define DECLG(r) float gxp##r = 0.0f;
    FOR_R(DECLG)

    float c0v = 0.0f, c1v = 0.0f;
    int loff = wave * 8192 + lane * 4;   // LDS float offset (pinned per iter)

    // AGPR input-GEMV partial: gxp_r = w_ih[rows(r)][col..col+16) @ iv4.
    // Each term: 1 v_accvgpr_read (kd dummy blocks LICM hoisting all 128
    // reads into spillable VGPRs) + 1 fmaf. Pure register work, no memory.
    #define ARD(src) { asm("v_accvgpr_read_b32 %0, %1" \
                           : "=v"(tt) : "a"(src), "v"(kd)); }
    #define GXA(r) { float a = 0.0f; float tt; \
        ARD(AI##r##_0)  a = fmaf(tt, iv4[0].x, a); \
        ARD(AI##r##_1)  a = fmaf(tt, iv4[0].y, a); \
        ARD(AI##r##_2)  a = fmaf(tt, iv4[0].z, a); \
        ARD(AI##r##_3)  a = fmaf(tt, iv4[0].w, a); \
        ARD(AI##r##_4)  a = fmaf(tt, iv4[1].x, a); \
        ARD(AI##r##_5)  a = fmaf(tt, iv4[1].y, a); \
        ARD(AI##r##_6)  a = fmaf(tt, iv4[1].z, a); \
        ARD(AI##r##_7)  a = fmaf(tt, iv4[1].w, a); \
        ARD(AI##r##_8)  a = fmaf(tt, iv4[2].x, a); \
        ARD(AI##r##_9)  a = fmaf(tt, iv4[2].y, a); \
        ARD(AI##r##_10) a = fmaf(tt, iv4[2].z, a); \
        ARD(AI##r##_11) a = fmaf(tt, iv4[2].w, a); \
        ARD(AI##r##_12) a = fmaf(tt, iv4[3].x, a); \
        ARD(AI##r##_13) a = fmaf(tt, iv4[3].y, a); \
        ARD(AI##r##_14) a = fmaf(tt, iv4[3].z, a); \
        ARD(AI##r##_15) a = fmaf(tt, iv4[3].w, a); \
        gxp##r = a; }

    // ---- prologue: L0 needs gx[0] before the first step ----
    if (!isL1) {
        float4 iv4[4];
        const float4* p = (const float4*)(x + col);
        iv4[0] = p[0]; iv4[1] = p[1]; iv4[2] = p[2]; iv4[3] = p[3];
        int kd = 0;
        FOR_R(GXA)
    }

    __syncthreads();   // LDS w_hh tile ready

    for (int k = 0; k <= TT + 1; ++k) {
        // pin LDS addressing so the (address-invariant) w_hh reads can't be
        // LICM-hoisted into spillable long-lived registers
        asm volatile("" : "+v"(loff));

        const int t = isL1 ? (k - 2) : k;

        // ================= CRITICAL phase (byte-identical to r13) ===========
        if (t >= 0 && t < TT) {
            float4 hp4[4];
            const float* hpv = (t > 0)
                ? (isL1 ? out + (size_t)(t - 1) * HH : ring + (size_t)((t - 1) & 3) * HH)
                : zbuf;
            load64B_llc(hp4, hpv + col);

            float acc0, acc1, acc2, acc3, acc4, acc5, acc6, acc7;
            #define DOTW(r) { float a = gxp##r; \
                const float4* wp = (const float4*)(ldsw + loff + (r) * 1024); \
                fma4(a, wp[0],   hp4[0]); fma4(a, wp[64],  hp4[1]); \
                fma4(a, wp[128], hp4[2]); fma4(a, wp[192], hp4[3]); \
                acc##r = a; }
            FOR_R(DOTW)

            #define REDW(m) \
                acc0 += __shfl_xor(acc0, m, 64); acc1 += __shfl_xor(acc1, m, 64); \
                acc2 += __shfl_xor(acc2, m, 64); acc3 += __shfl_xor(acc3, m, 64); \
                acc4 += __shfl_xor(acc4, m, 64); acc5 += __shfl_xor(acc5, m, 64); \
                acc6 += __shfl_xor(acc6, m, 64); acc7 += __shfl_xor(acc7, m, 64);
            REDW(1) REDW(2) REDW(4) REDW(8) REDW(16) REDW(32)

            // gates (PyTorch order i,f,g,o); bias added post-reduce
            const float gi0 = fsigmoid(acc0 + B0), gf0 = fsigmoid(acc1 + B1);
            const float gg0 = ftanh(acc2 + B2),    go0 = fsigmoid(acc3 + B3);
            c0v = gf0 * c0v + gi0 * gg0;
            const float h0 = go0 * ftanh(c0v);
            const float gi1 = fsigmoid(acc4 + B4), gf1 = fsigmoid(acc5 + B5);
            const float gg1 = ftanh(acc6 + B6),    go1 = fsigmoid(acc7 + B7);
            c1v = gf1 * c1v + gi1 * gg1;
            const float h1v = go1 * ftanh(c1v);

            if (lane == 0) {
                float2 hv = make_float2(h0, h1v);   // jbase, jbase+1 (jbase even)
                unsigned long long bits;
                __builtin_memcpy(&bits, &hv, 8);
                float* dstf = isL1 ? (out  + (size_t)t * HH + jbase)
                                   : (ring + (size_t)(t & 3) * HH + jbase);
                __hip_atomic_store((unsigned long long*)dstf, bits,
                                   __ATOMIC_RELAXED, __HIP_MEMORY_SCOPE_AGENT);
            }
        }

        __syncthreads();   // all 4 waves drain their h stores (vmcnt before s_barrier)

        if (k <= TT) {
            // ================= ARRIVE: plain per-WG epoch store ==============
            if (tid == 0) {
                asm volatile("s_waitcnt vmcnt(0)" ::: "memory");
                __hip_atomic_store(&slots[wg], (unsigned)(k + 1),
                                   __ATOMIC_RELAXED, __HIP_MEMORY_SCOPE_AGENT);
            }

            // ====== SLACK: gx for next timestep (AGPR w_ih, no L2 stream) ====
            {
                const int tn = t + 1;
                if (tn >= 0 && tn < TT) {
                    float4 iv4[4];
                    if (!isL1) {
                        const float4* p = (const float4*)(x + (size_t)tn * HH + col);
                        iv4[0] = p[0]; iv4[1] = p[1]; iv4[2] = p[2]; iv4[3] = p[3];
                    } else {
                        // h1[tn]: published by L0 at step tn, covered by the
                        // previous barrier
                        load64B_llc(iv4, ring + (size_t)(tn & 3) * HH + col);
                    }
                    int kd = k;
                    FOR_R(GXA)
                }
            }
            // anchor gx results so the slack work cannot sink past the poll
            asm volatile("" : "+v"(gxp0), "+v"(gxp1), "+v"(gxp2), "+v"(gxp3),
                             "+v"(gxp4), "+v"(gxp5), "+v"(gxp6), "+v"(gxp7));

            // ================= POLL: all 256 slots >= k+1 (thin) =============
            slot_barrier_wait(slots, (unsigned)(k + 1));
        }
    }
}

extern "C" void kernel_launch(void* const* d_in, const int* in_sizes, int n_in,
                              void* d_out, int out_size, void* d_ws, size_t ws_size,
                              hipStream_t stream) {
    (void)in_sizes; (void)n_in; (void)out_size; (void)ws_size;
    const float* x    = (const float*)d_in[0];
    const float* wih0 = (const float*)d_in[1];
    const float* whh0 = (const float*)d_in[2];
    const float* bih0 = (const float*)d_in[3];
    const float* bhh0 = (const float*)d_in[4];
    const float* wih1 = (const float*)d_in[5];
    const float* whh1 = (const float*)d_in[6];
    const float* bih1 = (const float*)d_in[7];
    const float* bhh1 = (const float*)d_in[8];
    float* out = (float*)d_out;

    // ws layout: [0,1024) slots (256 x 4B) | [4096,8192) zbuf |
    //            [8192,24576) ring (4 slots x 4 KB)
    unsigned* slots = (unsigned*)d_ws;
    float*    zbuf  = (float*)((char*)d_ws + 4096);
    float*    ring  = (float*)((char*)d_ws + 8192);

    // allow 128 KB dynamic LDS (160 KB available per CU on gfx950)
    (void)hipFuncSetAttribute((const void*)lstm2_persistent,
                              hipFuncAttributeMaxDynamicSharedMemorySize, LDS_BYTES);

    // zero slots + zbuf + ring every call (stream-ordered, graph-capturable)
    (void)hipMemsetAsync(d_ws, 0, 24576, stream);

    hipLaunchKernelGGL(lstm2_persistent, dim3(NWG), dim3(256), LDS_BYTES, stream,
                       x, wih0, whh0, bih0, bhh0,
                       wih1, whh1, bih1, bhh1, out, ring, zbuf, slots);
}